// Round 4
// baseline (1471.303 us; speedup 1.0000x reference)
//
#include <hip/hip_runtime.h>
#include <math.h>

#define BATCH 8192
#define DIM 1024
#define KDIM 512
#define ALPHA_C 0.1f
#define N_ITERS 50
#define POWER_ITERS 20
#define ROWS 32
#define ZSH 512

typedef short bf16x8 __attribute__((ext_vector_type(8)));
typedef float f32x4 __attribute__((ext_vector_type(4)));

__device__ __forceinline__ short f2bf(float x) {
  union { float f; unsigned u; } v; v.f = x;
  unsigned r = v.u + 0x7fffu + ((v.u >> 16) & 1u);
  return (short)(r >> 16);
}
__device__ __forceinline__ float bf2f(short s) {
  union { float f; unsigned u; } v;
  v.u = ((unsigned)(unsigned short)s) << 16;
  return v.f;
}

// XOR-swizzled LDS addressing (16B granule): row-major [ROWS][ZSH] shorts
__device__ __forceinline__ int zswz(int row, int col) {
  return row * ZSH + ((((col >> 3) ^ (row & 7)) << 3) | (col & 7));
}
__device__ __forceinline__ int zoff8(int row, int colg) {
  return row * ZSH + ((colg ^ (row & 7)) << 3);
}

// ---------------- K1: G = Wd^T Wd  (512x512 fp32) ----------------
__global__ __launch_bounds__(256) void k_gram(const float* __restrict__ Wd,
                                              float* __restrict__ G) {
  int tx = threadIdx.x & 15;
  int ty = threadIdx.x >> 4;
  int a0 = blockIdx.y * 64 + ty * 4;
  int b0 = blockIdx.x * 64 + tx * 4;
  float acc[4][4] = {};
  for (int d = 0; d < DIM; ++d) {
    float4 av = *(const float4*)&Wd[d * KDIM + a0];
    float4 bv = *(const float4*)&Wd[d * KDIM + b0];
    float aa[4] = {av.x, av.y, av.z, av.w};
    float bb[4] = {bv.x, bv.y, bv.z, bv.w};
#pragma unroll
    for (int i = 0; i < 4; ++i)
#pragma unroll
      for (int j = 0; j < 4; ++j) acc[i][j] += aa[i] * bb[j];
  }
#pragma unroll
  for (int i = 0; i < 4; ++i) {
    float4 o = make_float4(acc[i][0], acc[i][1], acc[i][2], acc[i][3]);
    *(float4*)&G[(a0 + i) * KDIM + b0] = o;
  }
}

// ---------------- K2: power iteration on G -> step, thr ----------------
__global__ __launch_bounds__(512) void k_power(const float* __restrict__ G,
                                               float* __restrict__ scal) {
  __shared__ float vbuf[KDIM];
  __shared__ float ubuf[KDIM];
  __shared__ float red[8];
  __shared__ float red2[8];
  __shared__ float stot;
  int tid = threadIdx.x;
  int lane = tid & 63;
  int wid = tid >> 6;
  vbuf[tid] = 1.0f;
  __syncthreads();

  for (int it = 0; it <= POWER_ITERS; ++it) {
#pragma unroll 4
    for (int r = wid; r < KDIM; r += 8) {
      const float4* gp = (const float4*)&G[r * KDIM + lane * 8];
      const float4* vp = (const float4*)&vbuf[lane * 8];
      float4 g0 = gp[0], g1 = gp[1];
      float4 v0 = vp[0], v1 = vp[1];
      float s = g0.x * v0.x + g0.y * v0.y + g0.z * v0.z + g0.w * v0.w +
                g1.x * v1.x + g1.y * v1.y + g1.z * v1.z + g1.w * v1.w;
#pragma unroll
      for (int off = 32; off; off >>= 1) s += __shfl_xor(s, off);
      if (lane == 0) ubuf[r] = s;
    }
    __syncthreads();
    if (it < POWER_ITERS) {
      float val = ubuf[tid] * ubuf[tid];
#pragma unroll
      for (int off = 32; off; off >>= 1) val += __shfl_xor(val, off);
      if (lane == 0) red[wid] = val;
      __syncthreads();
      if (tid == 0) {
        float t = 0.f;
        for (int i = 0; i < 8; ++i) t += red[i];
        stot = sqrtf(t) + 1e-12f;
      }
      __syncthreads();
      vbuf[tid] = ubuf[tid] / stot;
      __syncthreads();
    }
  }
  float nu = vbuf[tid] * ubuf[tid];
  float de = vbuf[tid] * vbuf[tid];
#pragma unroll
  for (int off = 32; off; off >>= 1) {
    nu += __shfl_xor(nu, off);
    de += __shfl_xor(de, off);
  }
  if (lane == 0) { red[wid] = nu; red2[wid] = de; }
  __syncthreads();
  if (tid == 0) {
    float n = 0.f, d = 0.f;
    for (int i = 0; i < 8; ++i) { n += red[i]; d += red2[i]; }
    float L = n / (d + 1e-12f);
    float step = 1.0f / L;
    scal[0] = step;
    scal[1] = step * ALPHA_C;
  }
}

// ---------------- K3: pack H = I - step*G (bf16 hi only, B-frag layout) ----
__global__ __launch_bounds__(256) void k_pack_h(const float* __restrict__ G,
                                                const float* __restrict__ scal,
                                                short* __restrict__ Hh) {
  int t = blockIdx.x * 256 + threadIdx.x;  // 512*512
  int k = t >> 9, n = t & 511;
  float step = scal[0];
  float h = ((k == n) ? 1.0f : 0.0f) - step * G[k * KDIM + n];
  int kk = k >> 5, q = (k >> 3) & 3, j = k & 7;
  Hh[((size_t)((kk * 4 + q) * 512 + n)) * 8 + j] = f2bf(h);
}

// Wph[((kk*4+q)*512 + n)*8 + j] = bf16(step*Wd[kk*32+q*8+j][n])
__global__ __launch_bounds__(256) void k_pack_w(const float* __restrict__ Wd,
                                                const float* __restrict__ scal,
                                                short* __restrict__ Wh) {
  int t = blockIdx.x * 256 + threadIdx.x;  // 1024*512
  int k = t >> 9, n = t & 511;
  float w = scal[0] * Wd[k * KDIM + n];
  int kk = k >> 5, q = (k >> 3) & 3, j = k & 7;
  Wh[((size_t)((kk * 4 + q) * 512 + n)) * 8 + j] = f2bf(w);
}

// Wth[((kk*4+q)*1024 + n)*8 + j] = bf16(Wd[n][kk*32+q*8+j])
__global__ __launch_bounds__(256) void k_pack_wt(const float* __restrict__ Wd,
                                                 short* __restrict__ Wh) {
  int t = blockIdx.x * 256 + threadIdx.x;  // 512*1024
  int k = t >> 10, n = t & 1023;
  float w = Wd[n * KDIM + k];
  int kk = k >> 5, q = (k >> 3) & 3, j = k & 7;
  Wh[((size_t)((kk * 4 + q) * 1024 + n)) * 8 + j] = f2bf(w);
}

// ---------------- K4: fused ISTA, 32 rows/block, 256 blocks ----------------
// Z stored as single bf16 in LDS (32 KB). H streamed from L2 every iteration
// (512 KB resident in each XCD's L2). No register cache -> no spills.
__global__ __launch_bounds__(512) void k_ista(
    const float* __restrict__ zex, const short* __restrict__ Hh,
    const short* __restrict__ Wph, const short* __restrict__ Wth,
    const float* __restrict__ scal, float* __restrict__ out,
    int* __restrict__ gcnt) {
  __shared__ short Zb[ROWS * ZSH];
  int tid = threadIdx.x;
  int lane = tid & 63, wid = tid >> 6;  // 8 waves
  int l15 = lane & 15, lq = lane >> 4;
  int rb = blockIdx.x * ROWS;
  float thr = scal[1];

  // ---------- stage 1: cs = step * X * Wd  (X = permuted zex) ----------
  // 4 passes: (half 0, hi), (half 0, lo), (half 1, hi), (half 1, lo)
  f32x4 cs[2][4];
#pragma unroll
  for (int rf = 0; rf < 2; ++rf)
#pragma unroll
    for (int cf = 0; cf < 4; ++cf) cs[rf][cf] = (f32x4){0.f, 0.f, 0.f, 0.f};

  int sr = tid >> 4, sc = tid & 15;  // 512 threads: 32 rows x 16 col-groups
  for (int half = 0; half < 2; ++half) {
    for (int part = 0; part < 2; ++part) {
      __syncthreads();
      {
        const float* src = &zex[(size_t)(rb + sr) * DIM + sc * 64 + half * 32];
#pragma unroll
        for (int m = 0; m < 32; m += 4) {
          float4 xv = *(const float4*)&src[m];
          float xs[4] = {xv.x, xv.y, xv.z, xv.w};
#pragma unroll
          for (int e = 0; e < 4; ++e) {
            int mm = m + e;
            int dd = ((mm >> 3) << 7) + ((mm & 7) << 4) + sc;
            short hi = f2bf(xs[e]);
            short v = part ? f2bf(xs[e] - bf2f(hi)) : hi;
            Zb[zswz(sr, dd)] = v;
          }
        }
      }
      __syncthreads();
#pragma unroll 2
      for (int kk = 0; kk < 16; ++kk) {
        int kkg = half * 16 + kk;
        bf16x8 a[2];
#pragma unroll
        for (int rf = 0; rf < 2; ++rf)
          a[rf] = *(const bf16x8*)&Zb[zoff8(rf * 16 + l15, kk * 4 + lq)];
#pragma unroll
        for (int cf = 0; cf < 4; ++cf) {
          int n = wid * 64 + cf * 16 + l15;
          bf16x8 bh = *(const bf16x8*)&Wph[((size_t)((kkg * 4 + lq) * 512 + n)) * 8];
#pragma unroll
          for (int rf = 0; rf < 2; ++rf)
            cs[rf][cf] = __builtin_amdgcn_mfma_f32_16x16x32_bf16(a[rf], bh, cs[rf][cf], 0, 0, 0);
        }
      }
    }
  }
  __syncthreads();

  // ---------- init: Z1 = ST(cs) ----------
#pragma unroll
  for (int rf = 0; rf < 2; ++rf)
#pragma unroll
    for (int cf = 0; cf < 4; ++cf) {
      int col = wid * 64 + cf * 16 + l15;
#pragma unroll
      for (int e = 0; e < 4; ++e) {
        float pre = cs[rf][cf][e];
        float mag = fmaxf(fabsf(pre) - thr, 0.f);
        float z = (pre >= 0.f) ? mag : -mag;
        int row = rf * 16 + lq * 4 + e;
        Zb[zswz(row, col)] = f2bf(z);
      }
    }
  __syncthreads();

  // ---------- iterations 1..49: Z = ST(Z*H + cs) ----------
  int cnt = 0;
#pragma unroll 1
  for (int it = 1; it < N_ITERS; ++it) {
    f32x4 acc[2][4];
#pragma unroll
    for (int rf = 0; rf < 2; ++rf)
#pragma unroll
      for (int cf = 0; cf < 4; ++cf) acc[rf][cf] = cs[rf][cf];

#pragma unroll
    for (int kk = 0; kk < 16; ++kk) {
      bf16x8 a[2];
#pragma unroll
      for (int rf = 0; rf < 2; ++rf)
        a[rf] = *(const bf16x8*)&Zb[zoff8(rf * 16 + l15, kk * 4 + lq)];
#pragma unroll
      for (int cf = 0; cf < 4; ++cf) {
        int n = wid * 64 + cf * 16 + l15;
        bf16x8 bh = *(const bf16x8*)&Hh[((size_t)((kk * 4 + lq) * 512 + n)) * 8];
#pragma unroll
        for (int rf = 0; rf < 2; ++rf)
          acc[rf][cf] = __builtin_amdgcn_mfma_f32_16x16x32_bf16(a[rf], bh, acc[rf][cf], 0, 0, 0);
      }
    }
    __syncthreads();  // all waves done reading Z
#pragma unroll
    for (int rf = 0; rf < 2; ++rf)
#pragma unroll
      for (int cf = 0; cf < 4; ++cf) {
        int col = wid * 64 + cf * 16 + l15;
#pragma unroll
        for (int e = 0; e < 4; ++e) {
          float pre = acc[rf][cf][e];
          float mag = fmaxf(fabsf(pre) - thr, 0.f);
          float z = (pre >= 0.f) ? mag : -mag;
          if (it == N_ITERS - 1) cnt += (fabsf(z) > 1e-6f) ? 1 : 0;
          int row = rf * 16 + lq * 4 + e;
          Zb[zswz(row, col)] = f2bf(z);
        }
      }
    __syncthreads();
  }

  // sparsity count
#pragma unroll
  for (int off = 32; off; off >>= 1) cnt += __shfl_xor(cnt, off);
  if (lane == 0) atomicAdd(gcnt, cnt);

  // ---------- stage 3: out = Z * Wd^T (1024 cols = 8 waves x 2 passes x 64) ----
#pragma unroll 1
  for (int pass = 0; pass < 2; ++pass) {
    f32x4 o[2][4];
#pragma unroll
    for (int rf = 0; rf < 2; ++rf)
#pragma unroll
      for (int cf = 0; cf < 4; ++cf) o[rf][cf] = (f32x4){0.f, 0.f, 0.f, 0.f};

#pragma unroll 2
    for (int kk = 0; kk < 16; ++kk) {
      bf16x8 a[2];
#pragma unroll
      for (int rf = 0; rf < 2; ++rf)
        a[rf] = *(const bf16x8*)&Zb[zoff8(rf * 16 + l15, kk * 4 + lq)];
#pragma unroll
      for (int cf = 0; cf < 4; ++cf) {
        int n = wid * 128 + pass * 64 + cf * 16 + l15;
        bf16x8 bh = *(const bf16x8*)&Wth[((size_t)((kk * 4 + lq) * 1024 + n)) * 8];
#pragma unroll
        for (int rf = 0; rf < 2; ++rf)
          o[rf][cf] = __builtin_amdgcn_mfma_f32_16x16x32_bf16(a[rf], bh, o[rf][cf], 0, 0, 0);
      }
    }
#pragma unroll
    for (int rf = 0; rf < 2; ++rf)
#pragma unroll
      for (int cf = 0; cf < 4; ++cf) {
        int col = wid * 128 + pass * 64 + cf * 16 + l15;
#pragma unroll
        for (int e = 0; e < 4; ++e) {
          int row = rb + rf * 16 + lq * 4 + e;
          out[(size_t)row * DIM + col] = o[rf][cf][e];
        }
      }
  }
}

// ---------------- K5: finalize sparsity scalar ----------------
__global__ void k_final(const int* __restrict__ gcnt, float* __restrict__ out) {
  out[(size_t)BATCH * DIM] = (float)(*gcnt) / (float)BATCH;
}

extern "C" void kernel_launch(void* const* d_in, const int* in_sizes, int n_in,
                              void* d_out, int out_size, void* d_ws,
                              size_t ws_size, hipStream_t stream) {
  (void)in_sizes; (void)n_in; (void)out_size; (void)ws_size;
  const float* zex = (const float*)d_in[0];
  const float* Wd = (const float*)d_in[1];
  float* out = (float*)d_out;
  char* ws = (char*)d_ws;

  float* G = (float*)ws;                       // 1 MB fp32
  float* scal = (float*)(ws + (1 << 20));      // step, thr
  int* gcnt = (int*)(ws + (1 << 20) + 64);
  short* Hh = (short*)(ws + 2 * (1 << 20));    // 512 KB
  short* Wph = (short*)(ws + 3 * (1 << 20));   // 1 MB
  short* Wth = (short*)(ws + 4 * (1 << 20));   // 1 MB

  hipMemsetAsync(gcnt, 0, sizeof(int), stream);
  dim3 gb(8, 8);
  k_gram<<<gb, 256, 0, stream>>>(Wd, G);
  k_power<<<1, 512, 0, stream>>>(G, scal);
  k_pack_h<<<1024, 256, 0, stream>>>(G, scal, Hh);
  k_pack_w<<<2048, 256, 0, stream>>>(Wd, scal, Wph);
  k_pack_wt<<<2048, 256, 0, stream>>>(Wd, Wth);
  k_ista<<<BATCH / ROWS, 512, 0, stream>>>(zex, Hh, Wph, Wth, scal, out, gcnt);
  k_final<<<1, 1, 0, stream>>>(gcnt, out);
}

// Round 5
// 935.820 us; speedup vs baseline: 1.5722x; 1.5722x over previous
//
#include <hip/hip_runtime.h>
#include <math.h>

#define BATCH 8192
#define DIM 1024
#define KDIM 512
#define ALPHA_C 0.1f
#define N_ITERS 50
#define POWER_ITERS 20
#define ROWS 32
#define ZSH 512

typedef short bf16x8 __attribute__((ext_vector_type(8)));
typedef float f32x4 __attribute__((ext_vector_type(4)));

__device__ __forceinline__ short f2bf(float x) {
  union { float f; unsigned u; } v; v.f = x;
  unsigned r = v.u + 0x7fffu + ((v.u >> 16) & 1u);
  return (short)(r >> 16);
}
__device__ __forceinline__ float bf2f(short s) {
  union { float f; unsigned u; } v;
  v.u = ((unsigned)(unsigned short)s) << 16;
  return v.f;
}

// XOR-swizzled LDS addressing (16B granule): row-major [ROWS][ZSH] shorts
__device__ __forceinline__ int zswz(int row, int col) {
  return row * ZSH + ((((col >> 3) ^ (row & 7)) << 3) | (col & 7));
}
__device__ __forceinline__ int zoff8(int row, int colg) {
  return row * ZSH + ((colg ^ (row & 7)) << 3);
}

// ---------------- K1: G = Wd^T Wd  (512x512 fp32) ----------------
__global__ __launch_bounds__(256) void k_gram(const float* __restrict__ Wd,
                                              float* __restrict__ G) {
  int tx = threadIdx.x & 15;
  int ty = threadIdx.x >> 4;
  int a0 = blockIdx.y * 64 + ty * 4;
  int b0 = blockIdx.x * 64 + tx * 4;
  float acc[4][4] = {};
  for (int d = 0; d < DIM; ++d) {
    float4 av = *(const float4*)&Wd[d * KDIM + a0];
    float4 bv = *(const float4*)&Wd[d * KDIM + b0];
    float aa[4] = {av.x, av.y, av.z, av.w};
    float bb[4] = {bv.x, bv.y, bv.z, bv.w};
#pragma unroll
    for (int i = 0; i < 4; ++i)
#pragma unroll
      for (int j = 0; j < 4; ++j) acc[i][j] += aa[i] * bb[j];
  }
#pragma unroll
  for (int i = 0; i < 4; ++i) {
    float4 o = make_float4(acc[i][0], acc[i][1], acc[i][2], acc[i][3]);
    *(float4*)&G[(a0 + i) * KDIM + b0] = o;
  }
}

// ---------------- K2: power iteration on G -> step, thr ----------------
__global__ __launch_bounds__(512) void k_power(const float* __restrict__ G,
                                               float* __restrict__ scal) {
  __shared__ float vbuf[KDIM];
  __shared__ float ubuf[KDIM];
  __shared__ float red[8];
  __shared__ float red2[8];
  __shared__ float stot;
  int tid = threadIdx.x;
  int lane = tid & 63;
  int wid = tid >> 6;
  vbuf[tid] = 1.0f;
  __syncthreads();

  for (int it = 0; it <= POWER_ITERS; ++it) {
#pragma unroll 4
    for (int r = wid; r < KDIM; r += 8) {
      const float4* gp = (const float4*)&G[r * KDIM + lane * 8];
      const float4* vp = (const float4*)&vbuf[lane * 8];
      float4 g0 = gp[0], g1 = gp[1];
      float4 v0 = vp[0], v1 = vp[1];
      float s = g0.x * v0.x + g0.y * v0.y + g0.z * v0.z + g0.w * v0.w +
                g1.x * v1.x + g1.y * v1.y + g1.z * v1.z + g1.w * v1.w;
#pragma unroll
      for (int off = 32; off; off >>= 1) s += __shfl_xor(s, off);
      if (lane == 0) ubuf[r] = s;
    }
    __syncthreads();
    if (it < POWER_ITERS) {
      float val = ubuf[tid] * ubuf[tid];
#pragma unroll
      for (int off = 32; off; off >>= 1) val += __shfl_xor(val, off);
      if (lane == 0) red[wid] = val;
      __syncthreads();
      if (tid == 0) {
        float t = 0.f;
        for (int i = 0; i < 8; ++i) t += red[i];
        stot = sqrtf(t) + 1e-12f;
      }
      __syncthreads();
      vbuf[tid] = ubuf[tid] / stot;
      __syncthreads();
    }
  }
  float nu = vbuf[tid] * ubuf[tid];
  float de = vbuf[tid] * vbuf[tid];
#pragma unroll
  for (int off = 32; off; off >>= 1) {
    nu += __shfl_xor(nu, off);
    de += __shfl_xor(de, off);
  }
  if (lane == 0) { red[wid] = nu; red2[wid] = de; }
  __syncthreads();
  if (tid == 0) {
    float n = 0.f, d = 0.f;
    for (int i = 0; i < 8; ++i) { n += red[i]; d += red2[i]; }
    float L = n / (d + 1e-12f);
    float step = 1.0f / L;
    scal[0] = step;
    scal[1] = step * ALPHA_C;
  }
}

// ---------------- K3: pack H = I - step*G (bf16 hi only, B-frag layout) ----
__global__ __launch_bounds__(256) void k_pack_h(const float* __restrict__ G,
                                                const float* __restrict__ scal,
                                                short* __restrict__ Hh) {
  int t = blockIdx.x * 256 + threadIdx.x;  // 512*512
  int k = t >> 9, n = t & 511;
  float step = scal[0];
  float h = ((k == n) ? 1.0f : 0.0f) - step * G[k * KDIM + n];
  int kk = k >> 5, q = (k >> 3) & 3, j = k & 7;
  Hh[((size_t)((kk * 4 + q) * 512 + n)) * 8 + j] = f2bf(h);
}

// Wph[((kk*4+q)*512 + n)*8 + j] = bf16(step*Wd[kk*32+q*8+j][n])
__global__ __launch_bounds__(256) void k_pack_w(const float* __restrict__ Wd,
                                                const float* __restrict__ scal,
                                                short* __restrict__ Wh) {
  int t = blockIdx.x * 256 + threadIdx.x;  // 1024*512
  int k = t >> 9, n = t & 511;
  float w = scal[0] * Wd[k * KDIM + n];
  int kk = k >> 5, q = (k >> 3) & 3, j = k & 7;
  Wh[((size_t)((kk * 4 + q) * 512 + n)) * 8 + j] = f2bf(w);
}

// Wth[((kk*4+q)*1024 + n)*8 + j] = bf16(Wd[n][kk*32+q*8+j])
__global__ __launch_bounds__(256) void k_pack_wt(const float* __restrict__ Wd,
                                                 short* __restrict__ Wh) {
  int t = blockIdx.x * 256 + threadIdx.x;  // 512*1024
  int k = t >> 10, n = t & 1023;
  float w = Wd[n * KDIM + k];
  int kk = k >> 5, q = (k >> 3) & 3, j = k & 7;
  Wh[((size_t)((kk * 4 + q) * 1024 + n)) * 8 + j] = f2bf(w);
}

// ---------------- K4: fused ISTA, 32 rows/block, 256 blocks ----------------
// Z single bf16 in LDS (32 KB). H streamed from L2 every iteration.
// kk index rotated by `it` so H load addresses are NOT loop-invariant:
// prevents LICM from hoisting 64 Hh loads and spilling them to scratch
// (R3/R4 pathology: 1.8 GB of scratch re-reads).
__global__ __launch_bounds__(512) void k_ista(
    const float* __restrict__ zex, const short* __restrict__ Hh,
    const short* __restrict__ Wph, const short* __restrict__ Wth,
    const float* __restrict__ scal, float* __restrict__ out,
    int* __restrict__ gcnt) {
  __shared__ short Zb[ROWS * ZSH];
  int tid = threadIdx.x;
  int lane = tid & 63, wid = tid >> 6;  // 8 waves
  int l15 = lane & 15, lq = lane >> 4;
  int rb = blockIdx.x * ROWS;
  float thr = scal[1];

  // ---------- stage 1: cs = step * X * Wd  (X = permuted zex) ----------
  f32x4 cs[2][4];
#pragma unroll
  for (int rf = 0; rf < 2; ++rf)
#pragma unroll
    for (int cf = 0; cf < 4; ++cf) cs[rf][cf] = (f32x4){0.f, 0.f, 0.f, 0.f};

  int sr = tid >> 4, sc = tid & 15;  // 512 threads: 32 rows x 16 col-groups
  for (int half = 0; half < 2; ++half) {
    for (int part = 0; part < 2; ++part) {
      __syncthreads();
      {
        const float* src = &zex[(size_t)(rb + sr) * DIM + sc * 64 + half * 32];
#pragma unroll
        for (int m = 0; m < 32; m += 4) {
          float4 xv = *(const float4*)&src[m];
          float xs[4] = {xv.x, xv.y, xv.z, xv.w};
#pragma unroll
          for (int e = 0; e < 4; ++e) {
            int mm = m + e;
            int dd = ((mm >> 3) << 7) + ((mm & 7) << 4) + sc;
            short hi = f2bf(xs[e]);
            short v = part ? f2bf(xs[e] - bf2f(hi)) : hi;
            Zb[zswz(sr, dd)] = v;
          }
        }
      }
      __syncthreads();
#pragma unroll 2
      for (int kk = 0; kk < 16; ++kk) {
        int kkg = half * 16 + kk;
        bf16x8 a[2];
#pragma unroll
        for (int rf = 0; rf < 2; ++rf)
          a[rf] = *(const bf16x8*)&Zb[zoff8(rf * 16 + l15, kk * 4 + lq)];
#pragma unroll
        for (int cf = 0; cf < 4; ++cf) {
          int n = wid * 64 + cf * 16 + l15;
          bf16x8 bh = *(const bf16x8*)&Wph[((size_t)((kkg * 4 + lq) * 512 + n)) * 8];
#pragma unroll
          for (int rf = 0; rf < 2; ++rf)
            cs[rf][cf] = __builtin_amdgcn_mfma_f32_16x16x32_bf16(a[rf], bh, cs[rf][cf], 0, 0, 0);
        }
      }
    }
  }
  __syncthreads();

  // ---------- init: Z1 = ST(cs) ----------
#pragma unroll
  for (int rf = 0; rf < 2; ++rf)
#pragma unroll
    for (int cf = 0; cf < 4; ++cf) {
      int col = wid * 64 + cf * 16 + l15;
#pragma unroll
      for (int e = 0; e < 4; ++e) {
        float pre = cs[rf][cf][e];
        float mag = fmaxf(fabsf(pre) - thr, 0.f);
        float z = (pre >= 0.f) ? mag : -mag;
        int row = rf * 16 + lq * 4 + e;
        Zb[zswz(row, col)] = f2bf(z);
      }
    }
  __syncthreads();

  // ---------- iterations 1..49: Z = ST(Z*H + cs) ----------
#pragma unroll 1
  for (int it = 1; it < N_ITERS; ++it) {
    int rot = it & 15;
    f32x4 acc[2][4];
#pragma unroll
    for (int rf = 0; rf < 2; ++rf)
#pragma unroll
      for (int cf = 0; cf < 4; ++cf) acc[rf][cf] = cs[rf][cf];

#pragma unroll 2
    for (int kk = 0; kk < 16; ++kk) {
      int kkr = (kk + rot) & 15;  // it-dependent: defeats cross-iter LICM
      bf16x8 a[2];
#pragma unroll
      for (int rf = 0; rf < 2; ++rf)
        a[rf] = *(const bf16x8*)&Zb[zoff8(rf * 16 + l15, kkr * 4 + lq)];
#pragma unroll
      for (int cf = 0; cf < 4; ++cf) {
        int n = wid * 64 + cf * 16 + l15;
        bf16x8 bh = *(const bf16x8*)&Hh[((size_t)((kkr * 4 + lq) * 512 + n)) * 8];
#pragma unroll
        for (int rf = 0; rf < 2; ++rf)
          acc[rf][cf] = __builtin_amdgcn_mfma_f32_16x16x32_bf16(a[rf], bh, acc[rf][cf], 0, 0, 0);
      }
    }
    __syncthreads();  // all waves done reading Z
#pragma unroll
    for (int rf = 0; rf < 2; ++rf)
#pragma unroll
      for (int cf = 0; cf < 4; ++cf) {
        int col = wid * 64 + cf * 16 + l15;
#pragma unroll
        for (int e = 0; e < 4; ++e) {
          float pre = acc[rf][cf][e];
          float mag = fmaxf(fabsf(pre) - thr, 0.f);
          float z = (pre >= 0.f) ? mag : -mag;
          int row = rf * 16 + lq * 4 + e;
          Zb[zswz(row, col)] = f2bf(z);
        }
      }
    __syncthreads();
  }

  // ---------- sparsity count: scan final Z in LDS (swizzle is a bijection) ----
  int cnt = 0;
#pragma unroll 4
  for (int i = tid; i < ROWS * ZSH; i += 512)
    cnt += (fabsf(bf2f(Zb[i])) > 1e-6f) ? 1 : 0;
#pragma unroll
  for (int off = 32; off; off >>= 1) cnt += __shfl_xor(cnt, off);
  if (lane == 0) atomicAdd(gcnt, cnt);

  // ---------- stage 3: out = Z * Wd^T (1024 cols = 8 waves x 2 passes x 64) ----
#pragma unroll 1
  for (int pass = 0; pass < 2; ++pass) {
    f32x4 o[2][4];
#pragma unroll
    for (int rf = 0; rf < 2; ++rf)
#pragma unroll
      for (int cf = 0; cf < 4; ++cf) o[rf][cf] = (f32x4){0.f, 0.f, 0.f, 0.f};

#pragma unroll 2
    for (int kk = 0; kk < 16; ++kk) {
      bf16x8 a[2];
#pragma unroll
      for (int rf = 0; rf < 2; ++rf)
        a[rf] = *(const bf16x8*)&Zb[zoff8(rf * 16 + l15, kk * 4 + lq)];
#pragma unroll
      for (int cf = 0; cf < 4; ++cf) {
        int n = wid * 128 + pass * 64 + cf * 16 + l15;
        bf16x8 bh = *(const bf16x8*)&Wth[((size_t)((kk * 4 + lq) * 1024 + n)) * 8];
#pragma unroll
        for (int rf = 0; rf < 2; ++rf)
          o[rf][cf] = __builtin_amdgcn_mfma_f32_16x16x32_bf16(a[rf], bh, o[rf][cf], 0, 0, 0);
      }
    }
#pragma unroll
    for (int rf = 0; rf < 2; ++rf)
#pragma unroll
      for (int cf = 0; cf < 4; ++cf) {
        int col = wid * 128 + pass * 64 + cf * 16 + l15;
#pragma unroll
        for (int e = 0; e < 4; ++e) {
          int row = rb + rf * 16 + lq * 4 + e;
          out[(size_t)row * DIM + col] = o[rf][cf][e];
        }
      }
  }
}

// ---------------- K5: finalize sparsity scalar ----------------
__global__ void k_final(const int* __restrict__ gcnt, float* __restrict__ out) {
  out[(size_t)BATCH * DIM] = (float)(*gcnt) / (float)BATCH;
}

extern "C" void kernel_launch(void* const* d_in, const int* in_sizes, int n_in,
                              void* d_out, int out_size, void* d_ws,
                              size_t ws_size, hipStream_t stream) {
  (void)in_sizes; (void)n_in; (void)out_size; (void)ws_size;
  const float* zex = (const float*)d_in[0];
  const float* Wd = (const float*)d_in[1];
  float* out = (float*)d_out;
  char* ws = (char*)d_ws;

  float* G = (float*)ws;                       // 1 MB fp32
  float* scal = (float*)(ws + (1 << 20));      // step, thr
  int* gcnt = (int*)(ws + (1 << 20) + 64);
  short* Hh = (short*)(ws + 2 * (1 << 20));    // 512 KB
  short* Wph = (short*)(ws + 3 * (1 << 20));   // 1 MB
  short* Wth = (short*)(ws + 4 * (1 << 20));   // 1 MB

  hipMemsetAsync(gcnt, 0, sizeof(int), stream);
  dim3 gb(8, 8);
  k_gram<<<gb, 256, 0, stream>>>(Wd, G);
  k_power<<<1, 512, 0, stream>>>(G, scal);
  k_pack_h<<<1024, 256, 0, stream>>>(G, scal, Hh);
  k_pack_w<<<2048, 256, 0, stream>>>(Wd, scal, Wph);
  k_pack_wt<<<2048, 256, 0, stream>>>(Wd, Wth);
  k_ista<<<BATCH / ROWS, 512, 0, stream>>>(zex, Hh, Wph, Wth, scal, out, gcnt);
  k_final<<<1, 1, 0, stream>>>(gcnt, out);
}